// Round 2
// baseline (3025.651 us; speedup 1.0000x reference)
//
#include <hip/hip_runtime.h>
#include <hip/hip_bf16.h>
#include <cstdio>

#define NN 50000
#define EE 640000
#define DD 128
#define HH 8
#define DH 16
#define FFD 256
#define CC 5
#define LL 6
#define EPSV 1e-5f

__device__ __forceinline__ float bfu2f(unsigned short u) {
  union { unsigned int i; float f; } x; x.i = ((unsigned int)u) << 16; return x.f;
}
__device__ __forceinline__ float dot4(const float4& a, const float4& b) {
  return a.x*b.x + a.y*b.y + a.z*b.z + a.w*b.w;
}
__device__ __forceinline__ void sfma4(float4& a, float c, float p, const float4& v) {
  a.x = a.x * c + p * v.x;
  a.y = a.y * c + p * v.y;
  a.z = a.z * c + p * v.z;
  a.w = a.w * c + p * v.w;
}

// ---------- dtype detect: g1 is all-ones. bf16 pair -> 0x3F803F80 ; fp32 -> 0x3F800000 ----------
__global__ void detect_kernel(const unsigned int* __restrict__ g1w, int* __restrict__ flag) {
  if (threadIdx.x == 0 && blockIdx.x == 0) *flag = (g1w[0] == 0x3F803F80u) ? 1 : 0;
}

// ---------- flag-aware convert to fp32 ----------
__global__ __launch_bounds__(256) void convert_kernel(const void* __restrict__ in,
                                                      float* __restrict__ out, int n,
                                                      const int* __restrict__ flag) {
  int i = blockIdx.x * blockDim.x + threadIdx.x;
  if (i >= n) return;
  if (*flag) out[i] = bfu2f(((const unsigned short*)in)[i]);
  else       out[i] = ((const float*)in)[i];
}

__global__ __launch_bounds__(256) void zero_kernel(int* __restrict__ p, int n) {
  int i = blockIdx.x * blockDim.x + threadIdx.x;
  if (i < n) p[i] = 0;
}

// ---------- CSR build (dst-indexed) ----------
__global__ __launch_bounds__(256) void count_kernel(const int* __restrict__ dst, int* __restrict__ counts) {
  int e = blockIdx.x * blockDim.x + threadIdx.x;
  if (e < EE) atomicAdd(&counts[dst[e]], 1);
}

__global__ __launch_bounds__(1024) void scan_kernel(const int* __restrict__ counts, int* __restrict__ row_ptr) {
  __shared__ int ss[1024];
  int t = threadIdx.x;
  const int CH = (NN + 1023) / 1024;  // 49
  int base = t * CH;
  int s = 0;
  for (int j = 0; j < CH; j++) { int idx = base + j; if (idx < NN) s += counts[idx]; }
  ss[t] = s; __syncthreads();
  for (int off = 1; off < 1024; off <<= 1) {
    int v = (t >= off) ? ss[t - off] : 0;
    __syncthreads();
    ss[t] += v;
    __syncthreads();
  }
  int run = ss[t] - s;  // exclusive prefix of this chunk
  for (int j = 0; j < CH; j++) {
    int idx = base + j;
    if (idx < NN) { row_ptr[idx] = run; run += counts[idx]; }
  }
  if (t == 0) row_ptr[NN] = EE;
}

__global__ __launch_bounds__(256) void fill_kernel(const int* __restrict__ src, const int* __restrict__ dst,
                                                   const int* __restrict__ row_ptr, int* __restrict__ cursor,
                                                   int* __restrict__ csr_src) {
  int e = blockIdx.x * blockDim.x + threadIdx.x;
  if (e < EE) {
    int d = dst[e];
    int pos = row_ptr[d] + atomicAdd(&cursor[d], 1);
    csr_src[pos] = src[e];
  }
}

// ---------- GEMM: C[M,NC] = A[M,K] @ B[K,NC] (all fp32) (+bias)(+resid)(+relu) ----------
template<int K, int NC, bool RELU>
__global__ __launch_bounds__(256) void gemm_kernel(const float* __restrict__ A,
                                                   const float* __restrict__ B,
                                                   const float* __restrict__ bias,
                                                   const float* __restrict__ resid,
                                                   float* __restrict__ C, int M) {
  constexpr int CG = NC / 4;     // col groups of 4
  constexpr int RG = 256 / CG;   // row groups
  constexpr int R  = 32 / RG;    // rows per thread
  __shared__ float As[32 * K];
  int row0 = blockIdx.x * 32;

  for (int idx = threadIdx.x * 4; idx < 32 * K; idx += 256 * 4) {
    int r = idx / K, c = idx - r * K;
    float4 val = make_float4(0.f, 0.f, 0.f, 0.f);
    if (row0 + r < M) val = *(const float4*)(A + (size_t)(row0 + r) * K + c);
    *(float4*)(As + idx) = val;
  }
  __syncthreads();

  int cg = threadIdx.x % CG, rg = threadIdx.x / CG;
  int j = cg * 4;
  float acc[R][4];
#pragma unroll
  for (int i = 0; i < R; i++) { acc[i][0] = 0.f; acc[i][1] = 0.f; acc[i][2] = 0.f; acc[i][3] = 0.f; }

#pragma unroll 8
  for (int kk = 0; kk < K; kk++) {
    float4 b = *(const float4*)(B + kk * NC + j);
#pragma unroll
    for (int i = 0; i < R; i++) {
      float a = As[(rg * R + i) * K + kk];
      acc[i][0] = fmaf(a, b.x, acc[i][0]);
      acc[i][1] = fmaf(a, b.y, acc[i][1]);
      acc[i][2] = fmaf(a, b.z, acc[i][2]);
      acc[i][3] = fmaf(a, b.w, acc[i][3]);
    }
  }

  float4 bv = make_float4(0.f, 0.f, 0.f, 0.f);
  if (bias) bv = *(const float4*)(bias + j);
#pragma unroll
  for (int i = 0; i < R; i++) {
    int r = row0 + rg * R + i;
    if (r >= M) continue;
    float4 o;
    o.x = acc[i][0] + bv.x; o.y = acc[i][1] + bv.y;
    o.z = acc[i][2] + bv.z; o.w = acc[i][3] + bv.w;
    if (resid) {
      float4 rr = *(const float4*)(resid + (size_t)r * NC + j);
      o.x += rr.x; o.y += rr.y; o.z += rr.z; o.w += rr.w;
    }
    if (RELU) {
      o.x = fmaxf(o.x, 0.f); o.y = fmaxf(o.y, 0.f);
      o.z = fmaxf(o.z, 0.f); o.w = fmaxf(o.w, 0.f);
    }
    *(float4*)(C + (size_t)r * NC + j) = o;
  }
}

// ---------- edge-softmax attention: one thread per (node, head), online softmax ----------
__global__ __launch_bounds__(256) void attn_kernel(const float4* __restrict__ q4,
                                                   const float4* __restrict__ k4,
                                                   const float4* __restrict__ v4,
                                                   const int* __restrict__ row_ptr,
                                                   const int* __restrict__ csr_src,
                                                   float4* __restrict__ o4) {
  int t = blockIdx.x * blockDim.x + threadIdx.x;
  if (t >= NN * HH) return;
  int n = t >> 3, h = t & 7;
  int qb = n * 32 + h * 4;  // float4 index into [N,128]
  float4 Q0 = q4[qb], Q1 = q4[qb + 1], Q2 = q4[qb + 2], Q3 = q4[qb + 3];
  float m = -3.0e38f, l = 0.f;
  float4 A0 = make_float4(0.f, 0.f, 0.f, 0.f), A1 = A0, A2 = A0, A3 = A0;
  int e0 = row_ptr[n], e1 = row_ptr[n + 1];
  for (int e = e0; e < e1; e++) {
    int s = csr_src[e];
    int kb = s * 32 + h * 4;
    float4 K0 = k4[kb], K1 = k4[kb + 1], K2 = k4[kb + 2], K3 = k4[kb + 3];
    float sc = (dot4(Q0, K0) + dot4(Q1, K1) + dot4(Q2, K2) + dot4(Q3, K3)) * 0.25f;
    float mn = fmaxf(m, sc);
    float cf = __expf(m - mn);
    float p  = __expf(sc - mn);
    l = l * cf + p;
    float4 V0 = v4[kb], V1 = v4[kb + 1], V2 = v4[kb + 2], V3 = v4[kb + 3];
    sfma4(A0, cf, p, V0); sfma4(A1, cf, p, V1);
    sfma4(A2, cf, p, V2); sfma4(A3, cf, p, V3);
    m = mn;
  }
  float inv = (l > 0.f) ? 1.f / l : 0.f;
  A0.x *= inv; A0.y *= inv; A0.z *= inv; A0.w *= inv;
  A1.x *= inv; A1.y *= inv; A1.z *= inv; A1.w *= inv;
  A2.x *= inv; A2.y *= inv; A2.z *= inv; A2.w *= inv;
  A3.x *= inv; A3.y *= inv; A3.z *= inv; A3.w *= inv;
  o4[qb] = A0; o4[qb + 1] = A1; o4[qb + 2] = A2; o4[qb + 3] = A3;
}

// ---------- BatchNorm (training mode over node dim) ----------
__global__ __launch_bounds__(256) void bn_stats_kernel(const float* __restrict__ y, float* __restrict__ stats) {
  int tid = threadIdx.x;
  int col = tid & 127, half = tid >> 7;
  float s = 0.f, sq = 0.f;
  for (int r = blockIdx.x * 2 + half; r < NN; r += gridDim.x * 2) {
    float v = y[(size_t)r * DD + col];
    s += v; sq = fmaf(v, v, sq);
  }
  __shared__ float red[512];
  red[tid] = s; red[256 + tid] = sq;
  __syncthreads();
  if (tid < 128) {
    atomicAdd(&stats[tid], red[tid] + red[tid + 128]);
    atomicAdd(&stats[128 + tid], red[256 + tid] + red[384 + tid]);
  }
}

__global__ void bn_finalize_kernel(const float* __restrict__ stats,
                                   const float* __restrict__ g,
                                   const float* __restrict__ b,
                                   float* __restrict__ ss) {
  int c = threadIdx.x;
  if (c < 128) {
    float mean = stats[c] * (1.f / NN);
    float var  = stats[128 + c] * (1.f / NN) - mean * mean;
    var = fmaxf(var, 0.f);  // guard fp rounding
    float sc = g[c] * rsqrtf(var + EPSV);
    float sh = b[c] - mean * sc;
    ss[c] = sc; ss[128 + c] = sh;
  }
}

__global__ __launch_bounds__(256) void bn_apply_kernel(const float4* __restrict__ y4,
                                                       const float4* __restrict__ ss4,
                                                       float4* __restrict__ x4) {
  int i = blockIdx.x * blockDim.x + threadIdx.x;
  const int total = NN * (DD / 4);
  if (i >= total) return;
  int c4 = i & 31;
  float4 v = y4[i], sc = ss4[c4], sh = ss4[32 + c4];
  float4 o;
  o.x = fmaf(v.x, sc.x, sh.x); o.y = fmaf(v.y, sc.y, sh.y);
  o.z = fmaf(v.z, sc.z, sh.z); o.w = fmaf(v.w, sc.w, sh.w);
  x4[i] = o;
}

// ---------- final projection [N,128] @ [128,5] + bias -> out (bf16 or fp32 per flag) ----------
__global__ __launch_bounds__(256) void proj_kernel(const float* __restrict__ x,
                                                   const float* __restrict__ Wp,
                                                   const float* __restrict__ bp,
                                                   void* __restrict__ out,
                                                   const int* __restrict__ flag) {
  __shared__ float W[DD * CC];
  __shared__ float bias[CC];
  for (int i = threadIdx.x; i < DD * CC; i += 256) W[i] = Wp[i];
  if (threadIdx.x < CC) bias[threadIdx.x] = bp[threadIdx.x];
  __syncthreads();
  int n = blockIdx.x * blockDim.x + threadIdx.x;
  if (n >= NN) return;
  float acc[CC];
#pragma unroll
  for (int c = 0; c < CC; c++) acc[c] = bias[c];
  const float4* xp = (const float4*)(x + (size_t)n * DD);
#pragma unroll
  for (int k4 = 0; k4 < DD / 4; k4++) {
    float4 a = xp[k4];
    const float* w = &W[k4 * 4 * CC];
#pragma unroll
    for (int c = 0; c < CC; c++)
      acc[c] += a.x * w[c] + a.y * w[CC + c] + a.z * w[2 * CC + c] + a.w * w[3 * CC + c];
  }
  if (*flag) {
    __hip_bfloat16* o16 = (__hip_bfloat16*)out;
#pragma unroll
    for (int c = 0; c < CC; c++) o16[(size_t)n * CC + c] = __float2bfloat16(acc[c]);
  } else {
    float* o32 = (float*)out;
#pragma unroll
    for (int c = 0; c < CC; c++) o32[(size_t)n * CC + c] = acc[c];
  }
}

extern "C" void kernel_launch(void* const* d_in, const int* in_sizes, int n_in,
                              void* d_out, int out_size, void* d_ws, size_t ws_size,
                              hipStream_t stream) {
  const int* ei = (const int*)d_in[1];

  char* p = (char*)d_ws;
  auto carve = [&](size_t bytes) { char* r = p; p += (bytes + 255) & ~(size_t)255; return (void*)r; };
  float* xf  = (float*)carve((size_t)NN * DD * 4);
  float* q   = (float*)carve((size_t)NN * DD * 4);
  float* k   = (float*)carve((size_t)NN * DD * 4);   // h (FFN hidden) aliases k+v (51.2MB)
  float* v   = (float*)carve((size_t)NN * DD * 4);
  float* t1  = (float*)carve((size_t)NN * DD * 4);
  float* h   = k;  // k,v dead when h live
  float* stats = (float*)carve(256 * 4);
  float* ss    = (float*)carve(256 * 4);
  int* row_ptr = (int*)carve((size_t)(NN + 1) * 4);
  int* cursor  = (int*)carve((size_t)NN * 4);
  int* csr_src = (int*)carve((size_t)EE * 4);
  int* flag    = (int*)carve(256);
  // fp32 copies of all float inputs
  float* Wq_f  = (float*)carve((size_t)LL * DD * DD * 4);
  float* Wk_f  = (float*)carve((size_t)LL * DD * DD * 4);
  float* Wv_f  = (float*)carve((size_t)LL * DD * DD * 4);
  float* Wo_f  = (float*)carve((size_t)LL * DD * DD * 4);
  float* g1_f  = (float*)carve((size_t)LL * DD * 4);
  float* bn1_f = (float*)carve((size_t)LL * DD * 4);
  float* W1_f  = (float*)carve((size_t)LL * DD * FFD * 4);
  float* bf1_f = (float*)carve((size_t)LL * FFD * 4);
  float* W2_f  = (float*)carve((size_t)LL * FFD * DD * 4);
  float* bf2_f = (float*)carve((size_t)LL * DD * 4);
  float* g2_f  = (float*)carve((size_t)LL * DD * 4);
  float* bn2_f = (float*)carve((size_t)LL * DD * 4);
  float* Wp_f  = (float*)carve((size_t)DD * CC * 4);
  float* bp_f  = (float*)carve((size_t)CC * 4);
  size_t need = (size_t)(p - (char*)d_ws);
  if (need > ws_size) {
    fprintf(stderr, "kernel_launch: workspace too small: need %zu, have %zu\n", need, ws_size);
    return;
  }

  const int* src  = ei;
  const int* dstp = ei + EE;

  // dtype detect (g1 is all-ones) then convert every float input to fp32
  detect_kernel<<<1, 64, 0, stream>>>((const unsigned int*)d_in[6], flag);
  auto conv = [&](int idx, float* dst, int n) {
    convert_kernel<<<(n + 255) / 256, 256, 0, stream>>>(d_in[idx], dst, n, flag);
  };
  conv(0, xf, NN * DD);
  conv(2, Wq_f, LL * DD * DD);
  conv(3, Wk_f, LL * DD * DD);
  conv(4, Wv_f, LL * DD * DD);
  conv(5, Wo_f, LL * DD * DD);
  conv(6, g1_f, LL * DD);
  conv(7, bn1_f, LL * DD);
  conv(8, W1_f, LL * DD * FFD);
  conv(9, bf1_f, LL * FFD);
  conv(10, W2_f, LL * FFD * DD);
  conv(11, bf2_f, LL * DD);
  conv(12, g2_f, LL * DD);
  conv(13, bn2_f, LL * DD);
  conv(14, Wp_f, DD * CC);
  conv(15, bp_f, CC);

  // build CSR by dst (edge_index is layer-invariant)
  zero_kernel<<<(NN + 255) / 256, 256, 0, stream>>>(cursor, NN);
  count_kernel<<<(EE + 255) / 256, 256, 0, stream>>>(dstp, cursor);
  scan_kernel<<<1, 1024, 0, stream>>>(cursor, row_ptr);
  zero_kernel<<<(NN + 255) / 256, 256, 0, stream>>>(cursor, NN);
  fill_kernel<<<(EE + 255) / 256, 256, 0, stream>>>(src, dstp, row_ptr, cursor, csr_src);

  const int gblocks = (NN + 31) / 32;
  for (int layer = 0; layer < LL; layer++) {
    const float* Wq_l = Wq_f + (size_t)layer * DD * DD;
    const float* Wk_l = Wk_f + (size_t)layer * DD * DD;
    const float* Wv_l = Wv_f + (size_t)layer * DD * DD;
    const float* Wo_l = Wo_f + (size_t)layer * DD * DD;
    const float* W1_l = W1_f + (size_t)layer * DD * FFD;
    const float* W2_l = W2_f + (size_t)layer * FFD * DD;

    // q,k,v projections
    gemm_kernel<128, 128, false><<<gblocks, 256, 0, stream>>>(xf, Wq_l, nullptr, nullptr, q, NN);
    gemm_kernel<128, 128, false><<<gblocks, 256, 0, stream>>>(xf, Wk_l, nullptr, nullptr, k, NN);
    gemm_kernel<128, 128, false><<<gblocks, 256, 0, stream>>>(xf, Wv_l, nullptr, nullptr, v, NN);

    // edge-restricted attention -> t1
    attn_kernel<<<(NN * HH + 255) / 256, 256, 0, stream>>>((const float4*)q, (const float4*)k, (const float4*)v,
                                                           row_ptr, csr_src, (float4*)t1);

    // out-proj + residual: yb = t1 @ Wo + xf   (yb aliases q, which is dead now)
    float* yb = q;
    gemm_kernel<128, 128, false><<<gblocks, 256, 0, stream>>>(t1, Wo_l, nullptr, xf, yb, NN);

    // BN1 -> xf
    zero_kernel<<<1, 256, 0, stream>>>((int*)stats, 256);
    bn_stats_kernel<<<256, 256, 0, stream>>>(yb, stats);
    bn_finalize_kernel<<<1, 128, 0, stream>>>(stats, g1_f + (size_t)layer * DD, bn1_f + (size_t)layer * DD, ss);
    bn_apply_kernel<<<(NN * 32 + 255) / 256, 256, 0, stream>>>((const float4*)yb, (const float4*)ss, (float4*)xf);

    // FFN (h aliases k/v which are dead until next layer's projections)
    gemm_kernel<128, 256, true><<<gblocks, 256, 0, stream>>>(xf, W1_l, bf1_f + (size_t)layer * FFD, nullptr, h, NN);
    gemm_kernel<256, 128, false><<<gblocks, 256, 0, stream>>>(h, W2_l, bf2_f + (size_t)layer * DD, xf, yb, NN);

    // BN2 -> xf
    zero_kernel<<<1, 256, 0, stream>>>((int*)stats, 256);
    bn_stats_kernel<<<256, 256, 0, stream>>>(yb, stats);
    bn_finalize_kernel<<<1, 128, 0, stream>>>(stats, g2_f + (size_t)layer * DD, bn2_f + (size_t)layer * DD, ss);
    bn_apply_kernel<<<(NN * 32 + 255) / 256, 256, 0, stream>>>((const float4*)yb, (const float4*)ss, (float4*)xf);
  }

  // final projection -> d_out
  proj_kernel<<<(NN + 255) / 256, 256, 0, stream>>>(xf, Wp_f, bp_f, d_out, flag);
}

// Round 3
// 1940.696 us; speedup vs baseline: 1.5591x; 1.5591x over previous
//
#include <hip/hip_runtime.h>
#include <hip/hip_bf16.h>
#include <cstdio>

#define NN 50000
#define EE 640000
#define DD 128
#define HH 8
#define DH 16
#define FFD 256
#define CC 5
#define LL 6
#define EPSV 1e-5f

typedef __attribute__((ext_vector_type(8))) short bf16x8;
typedef __attribute__((ext_vector_type(8))) unsigned short ushort8;
typedef __attribute__((ext_vector_type(4))) float f32x4;

__device__ __forceinline__ float bfu2f(unsigned short u) {
  union { unsigned int i; float f; } x; x.i = ((unsigned int)u) << 16; return x.f;
}
__device__ __forceinline__ unsigned short f2bf(float f) {
  union { float f; unsigned int i; } x; x.f = f;
  unsigned int r = (x.i + 0x7fffu + ((x.i >> 16) & 1u)) >> 16;
  return (unsigned short)r;
}

// ---------- dtype detect: g1 is all-ones. bf16 pair -> 0x3F803F80 ; fp32 -> 0x3F800000 ----------
__global__ void detect_kernel(const unsigned int* __restrict__ g1w, int* __restrict__ flag) {
  if (threadIdx.x == 0 && blockIdx.x == 0) *flag = (g1w[0] == 0x3F803F80u) ? 1 : 0;
}

__global__ __launch_bounds__(256) void convert_kernel(const void* __restrict__ in,
                                                      float* __restrict__ out, int n,
                                                      const int* __restrict__ flag) {
  int i = blockIdx.x * blockDim.x + threadIdx.x;
  if (i >= n) return;
  if (*flag) out[i] = bfu2f(((const unsigned short*)in)[i]);
  else       out[i] = ((const float*)in)[i];
}

__global__ __launch_bounds__(256) void to_bf16_kernel(const void* __restrict__ in,
                                                      unsigned short* __restrict__ out, int n,
                                                      const int* __restrict__ flag) {
  int i = blockIdx.x * blockDim.x + threadIdx.x;
  if (i >= n) return;
  if (*flag) out[i] = ((const unsigned short*)in)[i];
  else       out[i] = f2bf(((const float*)in)[i]);
}

// transpose+convert: in(base)+elt_off is [K,N] row-major -> out [N,K] bf16
__global__ __launch_bounds__(256) void transpose_off_kernel(const void* __restrict__ in, size_t elt_off,
                                                            unsigned short* __restrict__ out,
                                                            int K, int N, const int* __restrict__ flag) {
  int k = blockIdx.x;
  int use_bf = *flag;
  for (int n = threadIdx.x; n < N; n += 256) {
    unsigned short v;
    if (use_bf) v = ((const unsigned short*)in)[elt_off + (size_t)k * N + n];
    else        v = f2bf(((const float*)in)[elt_off + (size_t)k * N + n]);
    out[(size_t)n * K + k] = v;
  }
}

__global__ __launch_bounds__(256) void zero_kernel(int* __restrict__ p, int n) {
  int i = blockIdx.x * blockDim.x + threadIdx.x;
  if (i < n) p[i] = 0;
}

// ---------- CSR build (dst-indexed) ----------
__global__ __launch_bounds__(256) void count_kernel(const int* __restrict__ dst, int* __restrict__ counts) {
  int e = blockIdx.x * blockDim.x + threadIdx.x;
  if (e < EE) atomicAdd(&counts[dst[e]], 1);
}

__global__ __launch_bounds__(1024) void scan_kernel(const int* __restrict__ counts, int* __restrict__ row_ptr) {
  __shared__ int ss[1024];
  int t = threadIdx.x;
  const int CH = (NN + 1023) / 1024;  // 49
  int base = t * CH;
  int s = 0;
  for (int j = 0; j < CH; j++) { int idx = base + j; if (idx < NN) s += counts[idx]; }
  ss[t] = s; __syncthreads();
  for (int off = 1; off < 1024; off <<= 1) {
    int v = (t >= off) ? ss[t - off] : 0;
    __syncthreads();
    ss[t] += v;
    __syncthreads();
  }
  int run = ss[t] - s;
  for (int j = 0; j < CH; j++) {
    int idx = base + j;
    if (idx < NN) { row_ptr[idx] = run; run += counts[idx]; }
  }
  if (t == 0) row_ptr[NN] = EE;
}

__global__ __launch_bounds__(256) void fill_kernel(const int* __restrict__ src, const int* __restrict__ dst,
                                                   const int* __restrict__ row_ptr, int* __restrict__ cursor,
                                                   int* __restrict__ csr_src) {
  int e = blockIdx.x * blockDim.x + threadIdx.x;
  if (e < EE) {
    int d = dst[e];
    int pos = row_ptr[d] + atomicAdd(&cursor[d], 1);
    csr_src[pos] = src[e];
  }
}

// ---------- MFMA GEMM: C[M,*] = A[M,K](bf16) @ B via BT[NC,K](bf16); fused epilogue ----------
// 4 waves 2x2 -> block tile 128x128; wave tile 64x64 = 4x4 of 16x16x32 MFMA (m97 fragment layout).
template<int K, bool RELU, bool HASBIAS, bool HASRES, bool OUTBF>
__global__ __launch_bounds__(256) void mfma_gemm(const unsigned short* __restrict__ A,
                                                 const unsigned short* __restrict__ BT,
                                                 const float* __restrict__ bias,
                                                 const unsigned short* __restrict__ resid,
                                                 void* __restrict__ C, int M, int ldc) {
  int tid = threadIdx.x;
  int lane = tid & 63, wave = tid >> 6;
  int m0 = blockIdx.x * 128 + (wave >> 1) * 64;
  int n0 = blockIdx.y * 128 + (wave & 1) * 64;
  int lm = lane & 15;
  int quad = lane >> 4;
  int kq = quad * 8;

  int rowA[4];
#pragma unroll
  for (int r = 0; r < 4; r++) {
    int rr = m0 + 16 * r + lm;
    rowA[r] = (rr < M) ? rr : (M - 1);
  }

  f32x4 acc[4][4];
#pragma unroll
  for (int r = 0; r < 4; r++)
#pragma unroll
    for (int c = 0; c < 4; c++) acc[r][c] = (f32x4){0.f, 0.f, 0.f, 0.f};

#pragma unroll
  for (int k0 = 0; k0 < K; k0 += 32) {
    bf16x8 a[4], b[4];
#pragma unroll
    for (int r = 0; r < 4; r++)
      a[r] = *(const bf16x8*)(A + (size_t)rowA[r] * K + k0 + kq);
#pragma unroll
    for (int c = 0; c < 4; c++)
      b[c] = *(const bf16x8*)(BT + (size_t)(n0 + 16 * c + lm) * K + k0 + kq);
#pragma unroll
    for (int r = 0; r < 4; r++)
#pragma unroll
      for (int c = 0; c < 4; c++)
        acc[r][c] = __builtin_amdgcn_mfma_f32_16x16x32_bf16(a[r], b[c], acc[r][c], 0, 0, 0);
  }

#pragma unroll
  for (int c = 0; c < 4; c++) {
    int col = n0 + 16 * c + lm;
    float bv = HASBIAS ? bias[col] : 0.f;
#pragma unroll
    for (int r = 0; r < 4; r++) {
#pragma unroll
      for (int reg = 0; reg < 4; reg++) {
        int row = m0 + 16 * r + quad * 4 + reg;
        if (row < M) {
          float o = acc[r][c][reg] + bv;
          if (HASRES) o += bfu2f(resid[(size_t)row * ldc + col]);
          if (RELU) o = fmaxf(o, 0.f);
          size_t idx = (size_t)row * ldc + col;
          if (OUTBF) ((unsigned short*)C)[idx] = f2bf(o);
          else       ((float*)C)[idx] = o;
        }
      }
    }
  }
}

// ---------- edge-softmax attention: thread per (node, head), online softmax, bf16 fused qkv ----------
__global__ __launch_bounds__(256) void attn_kernel(const unsigned short* __restrict__ qkv,
                                                   const int* __restrict__ row_ptr,
                                                   const int* __restrict__ csr_src,
                                                   unsigned short* __restrict__ t1) {
  int t = blockIdx.x * blockDim.x + threadIdx.x;
  if (t >= NN * HH) return;
  int n = t >> 3, h = t & 7;
  const unsigned short* qp = qkv + (size_t)n * 384 + h * 16;
  float qf[16];
  {
    bf16x8 q0 = *(const bf16x8*)qp;
    bf16x8 q1 = *(const bf16x8*)(qp + 8);
#pragma unroll
    for (int i = 0; i < 8; i++) { qf[i] = bfu2f((unsigned short)q0[i]); qf[8 + i] = bfu2f((unsigned short)q1[i]); }
  }
  float m = -3.0e38f, l = 0.f;
  float A[16];
#pragma unroll
  for (int i = 0; i < 16; i++) A[i] = 0.f;
  int e0 = row_ptr[n], e1 = row_ptr[n + 1];
  for (int e = e0; e < e1; e++) {
    int s = csr_src[e];
    const unsigned short* kp = qkv + (size_t)s * 384 + 128 + h * 16;
    bf16x8 k0 = *(const bf16x8*)kp;
    bf16x8 k1 = *(const bf16x8*)(kp + 8);
    bf16x8 v0 = *(const bf16x8*)(kp + 128);
    bf16x8 v1 = *(const bf16x8*)(kp + 136);
    float sc = 0.f;
#pragma unroll
    for (int i = 0; i < 8; i++) {
      sc += qf[i] * bfu2f((unsigned short)k0[i]);
      sc += qf[8 + i] * bfu2f((unsigned short)k1[i]);
    }
    sc *= 0.25f;
    float mn = fmaxf(m, sc);
    float cf = __expf(m - mn);
    float p  = __expf(sc - mn);
    l = l * cf + p;
#pragma unroll
    for (int i = 0; i < 8; i++) {
      A[i]     = A[i]     * cf + p * bfu2f((unsigned short)v0[i]);
      A[8 + i] = A[8 + i] * cf + p * bfu2f((unsigned short)v1[i]);
    }
    m = mn;
  }
  float inv = (l > 0.f) ? 1.f / l : 0.f;
  ushort8 o0, o1;
#pragma unroll
  for (int i = 0; i < 8; i++) { o0[i] = f2bf(A[i] * inv); o1[i] = f2bf(A[8 + i] * inv); }
  unsigned short* op = t1 + (size_t)n * 128 + h * 16;
  *(ushort8*)op = o0;
  *(ushort8*)(op + 8) = o1;
}

// ---------- BatchNorm ----------
__global__ __launch_bounds__(256) void bn_stats_kernel(const float* __restrict__ y, float* __restrict__ stats) {
  int tid = threadIdx.x;
  int col = tid & 127, half = tid >> 7;
  float s = 0.f, sq = 0.f;
  for (int r = blockIdx.x * 2 + half; r < NN; r += gridDim.x * 2) {
    float v = y[(size_t)r * DD + col];
    s += v; sq = fmaf(v, v, sq);
  }
  __shared__ float red[512];
  red[tid] = s; red[256 + tid] = sq;
  __syncthreads();
  if (tid < 128) {
    atomicAdd(&stats[tid], red[tid] + red[tid + 128]);
    atomicAdd(&stats[128 + tid], red[256 + tid] + red[384 + tid]);
  }
}

__global__ void bn_finalize_kernel(const float* __restrict__ stats,
                                   const float* __restrict__ g,
                                   const float* __restrict__ b,
                                   float* __restrict__ ss) {
  int c = threadIdx.x;
  if (c < 128) {
    float mean = stats[c] * (1.f / NN);
    float var  = stats[128 + c] * (1.f / NN) - mean * mean;
    var = fmaxf(var, 0.f);
    float sc = g[c] * rsqrtf(var + EPSV);
    float sh = b[c] - mean * sc;
    ss[c] = sc; ss[128 + c] = sh;
  }
}

__global__ __launch_bounds__(256) void bn_apply_kernel(const float4* __restrict__ y4,
                                                       const float4* __restrict__ ss4,
                                                       ushort4* __restrict__ xb) {
  int i = blockIdx.x * blockDim.x + threadIdx.x;
  const int total = NN * (DD / 4);
  if (i >= total) return;
  int c4 = i & 31;
  float4 v = y4[i], sc = ss4[c4], sh = ss4[32 + c4];
  ushort4 o;
  o.x = f2bf(fmaf(v.x, sc.x, sh.x));
  o.y = f2bf(fmaf(v.y, sc.y, sh.y));
  o.z = f2bf(fmaf(v.z, sc.z, sh.z));
  o.w = f2bf(fmaf(v.w, sc.w, sh.w));
  xb[i] = o;
}

// ---------- final projection [N,128](bf16) @ [128,5] + bias ----------
__global__ __launch_bounds__(256) void proj_kernel(const unsigned short* __restrict__ x,
                                                   const float* __restrict__ Wp,
                                                   const float* __restrict__ bp,
                                                   void* __restrict__ out,
                                                   const int* __restrict__ flag) {
  __shared__ float W[DD * CC];
  __shared__ float bias[CC];
  for (int i = threadIdx.x; i < DD * CC; i += 256) W[i] = Wp[i];
  if (threadIdx.x < CC) bias[threadIdx.x] = bp[threadIdx.x];
  __syncthreads();
  int n = blockIdx.x * blockDim.x + threadIdx.x;
  if (n >= NN) return;
  float acc[CC];
#pragma unroll
  for (int c = 0; c < CC; c++) acc[c] = bias[c];
  const ushort4* xp = (const ushort4*)(x + (size_t)n * DD);
#pragma unroll
  for (int k4 = 0; k4 < DD / 4; k4++) {
    ushort4 u = xp[k4];
    float a0 = bfu2f(u.x), a1 = bfu2f(u.y), a2 = bfu2f(u.z), a3 = bfu2f(u.w);
    const float* w = &W[k4 * 4 * CC];
#pragma unroll
    for (int c = 0; c < CC; c++)
      acc[c] += a0 * w[c] + a1 * w[CC + c] + a2 * w[2 * CC + c] + a3 * w[3 * CC + c];
  }
  if (*flag) {
    __hip_bfloat16* o16 = (__hip_bfloat16*)out;
#pragma unroll
    for (int c = 0; c < CC; c++) o16[(size_t)n * CC + c] = __float2bfloat16(acc[c]);
  } else {
    float* o32 = (float*)out;
#pragma unroll
    for (int c = 0; c < CC; c++) o32[(size_t)n * CC + c] = acc[c];
  }
}

extern "C" void kernel_launch(void* const* d_in, const int* in_sizes, int n_in,
                              void* d_out, int out_size, void* d_ws, size_t ws_size,
                              hipStream_t stream) {
  const int* ei = (const int*)d_in[1];

  char* p = (char*)d_ws;
  auto carve = [&](size_t bytes) { char* r = p; p += (bytes + 255) & ~(size_t)255; return (void*)r; };
  unsigned short* xb   = (unsigned short*)carve((size_t)NN * DD * 2);
  unsigned short* qkv  = (unsigned short*)carve((size_t)NN * 384 * 2);
  unsigned short* t1   = (unsigned short*)carve((size_t)NN * DD * 2);
  unsigned short* hbuf = (unsigned short*)carve((size_t)NN * FFD * 2);
  float* y             = (float*)carve((size_t)NN * DD * 4);
  float* stats = (float*)carve(256 * 4);
  float* ss    = (float*)carve(256 * 4);
  int* row_ptr = (int*)carve((size_t)(NN + 1) * 4);
  int* cursor  = (int*)carve((size_t)NN * 4);
  int* csr_src = (int*)carve((size_t)EE * 4);
  int* flag    = (int*)carve(256);
  unsigned short* qkvT = (unsigned short*)carve((size_t)LL * 384 * DD * 2);
  unsigned short* WoT  = (unsigned short*)carve((size_t)LL * DD * DD * 2);
  unsigned short* W1T  = (unsigned short*)carve((size_t)LL * FFD * DD * 2);
  unsigned short* W2T  = (unsigned short*)carve((size_t)LL * DD * FFD * 2);
  float* g1_f  = (float*)carve((size_t)LL * DD * 4);
  float* bn1_f = (float*)carve((size_t)LL * DD * 4);
  float* bf1_f = (float*)carve((size_t)LL * FFD * 4);
  float* bf2_f = (float*)carve((size_t)LL * DD * 4);
  float* g2_f  = (float*)carve((size_t)LL * DD * 4);
  float* bn2_f = (float*)carve((size_t)LL * DD * 4);
  float* Wp_f  = (float*)carve((size_t)DD * CC * 4);
  float* bp_f  = (float*)carve((size_t)CC * 4);
  size_t need = (size_t)(p - (char*)d_ws);
  if (need > ws_size) {
    fprintf(stderr, "kernel_launch: workspace too small: need %zu, have %zu\n", need, ws_size);
    return;
  }

  const int* src  = ei;
  const int* dstp = ei + EE;

  detect_kernel<<<1, 64, 0, stream>>>((const unsigned int*)d_in[6], flag);
  to_bf16_kernel<<<(NN * DD + 255) / 256, 256, 0, stream>>>(d_in[0], xb, NN * DD, flag);

  auto conv = [&](int idx, float* dst, int n) {
    convert_kernel<<<(n + 255) / 256, 256, 0, stream>>>(d_in[idx], dst, n, flag);
  };
  conv(6, g1_f, LL * DD);   conv(7, bn1_f, LL * DD);
  conv(9, bf1_f, LL * FFD); conv(11, bf2_f, LL * DD);
  conv(12, g2_f, LL * DD);  conv(13, bn2_f, LL * DD);
  conv(14, Wp_f, DD * CC);  conv(15, bp_f, CC);

  // weight transposes -> bf16 [N,K]; qkvT fused rows [Wq^T | Wk^T | Wv^T]
  for (int l = 0; l < LL; l++) {
    size_t o2 = (size_t)l * DD * DD;
    transpose_off_kernel<<<DD, 256, 0, stream>>>(d_in[2], o2, qkvT + (size_t)l * 384 * DD, DD, DD, flag);
    transpose_off_kernel<<<DD, 256, 0, stream>>>(d_in[3], o2, qkvT + (size_t)l * 384 * DD + DD * DD, DD, DD, flag);
    transpose_off_kernel<<<DD, 256, 0, stream>>>(d_in[4], o2, qkvT + (size_t)l * 384 * DD + 2 * DD * DD, DD, DD, flag);
    transpose_off_kernel<<<DD, 256, 0, stream>>>(d_in[5], o2, WoT + (size_t)l * DD * DD, DD, DD, flag);
    transpose_off_kernel<<<DD, 256, 0, stream>>>(d_in[8], (size_t)l * DD * FFD, W1T + (size_t)l * FFD * DD, DD, FFD, flag);
    transpose_off_kernel<<<FFD, 256, 0, stream>>>(d_in[10], (size_t)l * FFD * DD, W2T + (size_t)l * DD * FFD, FFD, DD, flag);
  }

  zero_kernel<<<(NN + 255) / 256, 256, 0, stream>>>(cursor, NN);
  count_kernel<<<(EE + 255) / 256, 256, 0, stream>>>(dstp, cursor);
  scan_kernel<<<1, 1024, 0, stream>>>(cursor, row_ptr);
  zero_kernel<<<(NN + 255) / 256, 256, 0, stream>>>(cursor, NN);
  fill_kernel<<<(EE + 255) / 256, 256, 0, stream>>>(src, dstp, row_ptr, cursor, csr_src);

  const int gm = (NN + 127) / 128;
  for (int layer = 0; layer < LL; layer++) {
    const unsigned short* qkvT_l = qkvT + (size_t)layer * 384 * DD;
    const unsigned short* WoT_l  = WoT  + (size_t)layer * DD * DD;
    const unsigned short* W1T_l  = W1T  + (size_t)layer * FFD * DD;
    const unsigned short* W2T_l  = W2T  + (size_t)layer * DD * FFD;

    mfma_gemm<128, false, false, false, true><<<dim3(gm, 3), 256, 0, stream>>>(
        xb, qkvT_l, nullptr, nullptr, qkv, NN, 384);
    attn_kernel<<<(NN * HH + 255) / 256, 256, 0, stream>>>(qkv, row_ptr, csr_src, t1);
    mfma_gemm<128, false, false, true, false><<<dim3(gm, 1), 256, 0, stream>>>(
        t1, WoT_l, nullptr, xb, y, NN, 128);
    zero_kernel<<<1, 256, 0, stream>>>((int*)stats, 256);
    bn_stats_kernel<<<256, 256, 0, stream>>>(y, stats);
    bn_finalize_kernel<<<1, 128, 0, stream>>>(stats, g1_f + (size_t)layer * DD, bn1_f + (size_t)layer * DD, ss);
    bn_apply_kernel<<<(NN * 32 + 255) / 256, 256, 0, stream>>>((const float4*)y, (const float4*)ss, (ushort4*)xb);

    mfma_gemm<128, true, true, false, true><<<dim3(gm, 2), 256, 0, stream>>>(
        xb, W1T_l, bf1_f + (size_t)layer * FFD, nullptr, hbuf, NN, 256);
    mfma_gemm<256, false, true, true, false><<<dim3(gm, 1), 256, 0, stream>>>(
        hbuf, W2T_l, bf2_f + (size_t)layer * DD, xb, y, NN, 128);
    zero_kernel<<<1, 256, 0, stream>>>((int*)stats, 256);
    bn_stats_kernel<<<256, 256, 0, stream>>>(y, stats);
    bn_finalize_kernel<<<1, 128, 0, stream>>>(stats, g2_f + (size_t)layer * DD, bn2_f + (size_t)layer * DD, ss);
    bn_apply_kernel<<<(NN * 32 + 255) / 256, 256, 0, stream>>>((const float4*)y, (const float4*)ss, (ushort4*)xb);
  }

  proj_kernel<<<(NN + 255) / 256, 256, 0, stream>>>(xb, Wp_f, bp_f, d_out, flag);
}

// Round 4
// 1453.563 us; speedup vs baseline: 2.0815x; 1.3351x over previous
//
#include <hip/hip_runtime.h>
#include <hip/hip_bf16.h>
#include <cstdio>

#define NN 50000
#define EE 640000
#define DD 128
#define HH 8
#define DH 16
#define FFD 256
#define CC 5
#define LL 6
#define EPSV 1e-5f

typedef __attribute__((ext_vector_type(8))) short bf16x8;
typedef __attribute__((ext_vector_type(8))) unsigned short ushort8;
typedef __attribute__((ext_vector_type(4))) float f32x4;

__device__ __forceinline__ float bfu2f(unsigned short u) {
  union { unsigned int i; float f; } x; x.i = ((unsigned int)u) << 16; return x.f;
}
__device__ __forceinline__ unsigned short f2bf(float f) {
  union { float f; unsigned int i; } x; x.f = f;
  unsigned int r = (x.i + 0x7fffu + ((x.i >> 16) & 1u)) >> 16;
  return (unsigned short)r;
}

// ---------- dtype detect: g1 is all-ones. bf16 pair -> 0x3F803F80 ; fp32 -> 0x3F800000 ----------
__global__ void detect_kernel(const unsigned int* __restrict__ g1w, int* __restrict__ flag) {
  if (threadIdx.x == 0 && blockIdx.x == 0) *flag = (g1w[0] == 0x3F803F80u) ? 1 : 0;
}

// ---------- batched small-param convert: 8 jobs, one block each ----------
struct ConvJobs { const void* in[8]; float* out[8]; int n[8]; };
__global__ __launch_bounds__(256) void convert_batch_kernel(ConvJobs jobs, const int* __restrict__ flag) {
  int b = blockIdx.x;
  const void* in = jobs.in[b];
  float* out = jobs.out[b];
  int n = jobs.n[b];
  int use_bf = *flag;
  for (int i = threadIdx.x; i < n; i += 256) {
    if (use_bf) out[i] = bfu2f(((const unsigned short*)in)[i]);
    else        out[i] = ((const float*)in)[i];
  }
}

__global__ __launch_bounds__(256) void to_bf16_kernel(const void* __restrict__ in,
                                                      unsigned short* __restrict__ out, int n,
                                                      const int* __restrict__ flag) {
  int i = blockIdx.x * blockDim.x + threadIdx.x;
  if (i >= n) return;
  if (*flag) out[i] = ((const unsigned short*)in)[i];
  else       out[i] = f2bf(((const float*)in)[i]);
}

// ---------- batched weight transposes -> bf16 [N,K] ----------
// qkv: grid (DD, 3, LL); in[which] is [L,128,128]; out row block which*128 of qkvT[l] (=[384,128])
__global__ __launch_bounds__(256) void t_qkv_kernel(const void* __restrict__ wq, const void* __restrict__ wk,
                                                    const void* __restrict__ wv,
                                                    unsigned short* __restrict__ qkvT,
                                                    const int* __restrict__ flag) {
  int k = blockIdx.x, which = blockIdx.y, l = blockIdx.z;
  const void* in = (which == 0) ? wq : (which == 1) ? wk : wv;
  size_t off = (size_t)l * DD * DD;
  unsigned short* out = qkvT + (size_t)l * 384 * DD + (size_t)which * DD * DD;
  int use_bf = *flag;
  for (int n = threadIdx.x; n < DD; n += 256) {
    unsigned short v;
    if (use_bf) v = ((const unsigned short*)in)[off + (size_t)k * DD + n];
    else        v = f2bf(((const float*)in)[off + (size_t)k * DD + n]);
    out[(size_t)n * DD + k] = v;
  }
}

// generic: grid (K, LL); in is [L,K,N] -> out[l] is [N,K]
__global__ __launch_bounds__(256) void t_w_kernel(const void* __restrict__ in,
                                                  unsigned short* __restrict__ out,
                                                  int K, int N, const int* __restrict__ flag) {
  int k = blockIdx.x, l = blockIdx.y;
  size_t off = (size_t)l * K * N;
  unsigned short* o = out + (size_t)l * K * N;
  int use_bf = *flag;
  for (int n = threadIdx.x; n < N; n += 256) {
    unsigned short v;
    if (use_bf) v = ((const unsigned short*)in)[off + (size_t)k * N + n];
    else        v = f2bf(((const float*)in)[off + (size_t)k * N + n]);
    o[(size_t)n * K + k] = v;
  }
}

__global__ __launch_bounds__(256) void zero_kernel(int* __restrict__ p, int n) {
  int i = blockIdx.x * blockDim.x + threadIdx.x;
  if (i < n) p[i] = 0;
}

// ---------- CSR build (dst-indexed) ----------
__global__ __launch_bounds__(256) void count_kernel(const int* __restrict__ dst, int* __restrict__ counts) {
  int e = blockIdx.x * blockDim.x + threadIdx.x;
  if (e < EE) atomicAdd(&counts[dst[e]], 1);
}

// parallel exclusive scan, 3 phases
__global__ __launch_bounds__(256) void scan1_kernel(const int* __restrict__ counts,
                                                    int* __restrict__ row_ptr, int* __restrict__ partials) {
  __shared__ int sh[256];
  int t = threadIdx.x;
  int i = blockIdx.x * 256 + t;
  int v = (i < NN) ? counts[i] : 0;
  sh[t] = v; __syncthreads();
#pragma unroll
  for (int off = 1; off < 256; off <<= 1) {
    int u = (t >= off) ? sh[t - off] : 0;
    __syncthreads();
    sh[t] += u;
    __syncthreads();
  }
  if (i < NN) row_ptr[i] = sh[t] - v;  // exclusive within block
  if (t == 255) partials[blockIdx.x] = sh[t];
}

__global__ __launch_bounds__(256) void scan2_kernel(int* __restrict__ partials, int nb) {
  __shared__ int sh[256];
  int t = threadIdx.x;
  int v = (t < nb) ? partials[t] : 0;
  sh[t] = v; __syncthreads();
#pragma unroll
  for (int off = 1; off < 256; off <<= 1) {
    int u = (t >= off) ? sh[t - off] : 0;
    __syncthreads();
    sh[t] += u;
    __syncthreads();
  }
  if (t < nb) partials[t] = sh[t] - v;  // exclusive
}

__global__ __launch_bounds__(256) void scan3_kernel(int* __restrict__ row_ptr, const int* __restrict__ partials) {
  int i = blockIdx.x * 256 + threadIdx.x;
  if (i < NN) row_ptr[i] += partials[blockIdx.x];
  if (i == 0) row_ptr[NN] = EE;
}

__global__ __launch_bounds__(256) void fill_kernel(const int* __restrict__ src, const int* __restrict__ dst,
                                                   const int* __restrict__ row_ptr, int* __restrict__ cursor,
                                                   int* __restrict__ csr_src) {
  int e = blockIdx.x * blockDim.x + threadIdx.x;
  if (e < EE) {
    int d = dst[e];
    int pos = row_ptr[d] + atomicAdd(&cursor[d], 1);
    csr_src[pos] = src[e];
  }
}

// ---------- MFMA GEMM: C[M,*] = A[M,K](bf16) @ BT[NC,K](bf16); fused epilogue (+BN stats) ----------
// 4 waves 2x2 -> block tile 128x128; wave tile 64x64 = 4x4 of 16x16x32 MFMA (m97 fragment layout).
// STATS: accumulate per-column sum/sumsq of the fp32 output into stats[0:128]/[128:256]
// (only valid when gridDim.y==1 and output has 128 cols).
template<int K, bool RELU, bool HASBIAS, bool HASRES, bool OUTBF, bool STATS>
__global__ __launch_bounds__(256) void mfma_gemm(const unsigned short* __restrict__ A,
                                                 const unsigned short* __restrict__ BT,
                                                 const float* __restrict__ bias,
                                                 const unsigned short* __restrict__ resid,
                                                 void* __restrict__ C, float* __restrict__ stats,
                                                 int M, int ldc) {
  __shared__ float lsum[128];
  __shared__ float lsq[128];
  int tid = threadIdx.x;
  int lane = tid & 63, wave = tid >> 6;
  int m0 = blockIdx.x * 128 + (wave >> 1) * 64;
  int n0 = blockIdx.y * 128 + (wave & 1) * 64;
  int lm = lane & 15;
  int quad = lane >> 4;
  int kq = quad * 8;

  int rowA[4];
#pragma unroll
  for (int r = 0; r < 4; r++) {
    int rr = m0 + 16 * r + lm;
    rowA[r] = (rr < M) ? rr : (M - 1);
  }

  f32x4 acc[4][4];
#pragma unroll
  for (int r = 0; r < 4; r++)
#pragma unroll
    for (int c = 0; c < 4; c++) acc[r][c] = (f32x4){0.f, 0.f, 0.f, 0.f};

#pragma unroll
  for (int k0 = 0; k0 < K; k0 += 32) {
    bf16x8 a[4], b[4];
#pragma unroll
    for (int r = 0; r < 4; r++)
      a[r] = *(const bf16x8*)(A + (size_t)rowA[r] * K + k0 + kq);
#pragma unroll
    for (int c = 0; c < 4; c++)
      b[c] = *(const bf16x8*)(BT + (size_t)(n0 + 16 * c + lm) * K + k0 + kq);
#pragma unroll
    for (int r = 0; r < 4; r++)
#pragma unroll
      for (int c = 0; c < 4; c++)
        acc[r][c] = __builtin_amdgcn_mfma_f32_16x16x32_bf16(a[r], b[c], acc[r][c], 0, 0, 0);
  }

  if (STATS) {
    if (tid < 128) { lsum[tid] = 0.f; lsq[tid] = 0.f; }
    __syncthreads();
  }

#pragma unroll
  for (int c = 0; c < 4; c++) {
    int col = n0 + 16 * c + lm;
    float bv = HASBIAS ? bias[col] : 0.f;
    float ps = 0.f, pss = 0.f;
#pragma unroll
    for (int r = 0; r < 4; r++) {
#pragma unroll
      for (int reg = 0; reg < 4; reg++) {
        int row = m0 + 16 * r + quad * 4 + reg;
        if (row < M) {
          float o = acc[r][c][reg] + bv;
          if (HASRES) o += bfu2f(resid[(size_t)row * ldc + col]);
          if (RELU) o = fmaxf(o, 0.f);
          size_t idx = (size_t)row * ldc + col;
          if (OUTBF) ((unsigned short*)C)[idx] = f2bf(o);
          else       ((float*)C)[idx] = o;
          if (STATS) { ps += o; pss = fmaf(o, o, pss); }
        }
      }
    }
    if (STATS) {
      int bcol = (wave & 1) * 64 + 16 * c + lm;
      atomicAdd(&lsum[bcol], ps);
      atomicAdd(&lsq[bcol], pss);
    }
  }
  if (STATS) {
    __syncthreads();
    if (tid < 128) {
      atomicAdd(&stats[tid], lsum[tid]);
      atomicAdd(&stats[128 + tid], lsq[tid]);
    }
  }
}

// ---------- edge-softmax attention: thread per (node, head), online softmax, 2-deep pipeline ----------
__global__ __launch_bounds__(256) void attn_kernel(const unsigned short* __restrict__ qkv,
                                                   const int* __restrict__ row_ptr,
                                                   const int* __restrict__ csr_src,
                                                   unsigned short* __restrict__ t1) {
  int t = blockIdx.x * blockDim.x + threadIdx.x;
  if (t >= NN * HH) return;
  int n = t >> 3, h = t & 7;
  const unsigned short* qp = qkv + (size_t)n * 384 + h * 16;
  float qf[16];
  {
    bf16x8 q0 = *(const bf16x8*)qp;
    bf16x8 q1 = *(const bf16x8*)(qp + 8);
#pragma unroll
    for (int i = 0; i < 8; i++) { qf[i] = bfu2f((unsigned short)q0[i]); qf[8 + i] = bfu2f((unsigned short)q1[i]); }
  }
  float m = -3.0e38f, l = 0.f;
  float A[16];
#pragma unroll
  for (int i = 0; i < 16; i++) A[i] = 0.f;
  int e0 = row_ptr[n], e1 = row_ptr[n + 1];
  if (e0 < e1) {
    int s = csr_src[e0];
    const unsigned short* kp = qkv + (size_t)s * 384 + 128 + h * 16;
    bf16x8 k0 = *(const bf16x8*)kp;
    bf16x8 k1 = *(const bf16x8*)(kp + 8);
    bf16x8 v0 = *(const bf16x8*)(kp + 128);
    bf16x8 v1 = *(const bf16x8*)(kp + 136);
    for (int e = e0; e < e1; e++) {
      // issue next edge's loads before consuming current (software pipeline)
      int sn = csr_src[(e + 1 < e1) ? e + 1 : e];
      const unsigned short* kpn = qkv + (size_t)sn * 384 + 128 + h * 16;
      bf16x8 nk0 = *(const bf16x8*)kpn;
      bf16x8 nk1 = *(const bf16x8*)(kpn + 8);
      bf16x8 nv0 = *(const bf16x8*)(kpn + 128);
      bf16x8 nv1 = *(const bf16x8*)(kpn + 136);

      float sc = 0.f;
#pragma unroll
      for (int i = 0; i < 8; i++) {
        sc += qf[i] * bfu2f((unsigned short)k0[i]);
        sc += qf[8 + i] * bfu2f((unsigned short)k1[i]);
      }
      sc *= 0.25f;
      float mn = fmaxf(m, sc);
      float cf = __expf(m - mn);
      float p  = __expf(sc - mn);
      l = l * cf + p;
#pragma unroll
      for (int i = 0; i < 8; i++) {
        A[i]     = A[i]     * cf + p * bfu2f((unsigned short)v0[i]);
        A[8 + i] = A[8 + i] * cf + p * bfu2f((unsigned short)v1[i]);
      }
      m = mn;
      k0 = nk0; k1 = nk1; v0 = nv0; v1 = nv1;
    }
  }
  float inv = (l > 0.f) ? 1.f / l : 0.f;
  ushort8 o0, o1;
#pragma unroll
  for (int i = 0; i < 8; i++) { o0[i] = f2bf(A[i] * inv); o1[i] = f2bf(A[8 + i] * inv); }
  unsigned short* op = t1 + (size_t)n * 128 + h * 16;
  *(ushort8*)op = o0;
  *(ushort8*)(op + 8) = o1;
}

// ---------- BatchNorm finalize (also re-zeroes stats for next accumulation) ----------
__global__ void bn_finalize_kernel(float* __restrict__ stats,
                                   const float* __restrict__ g,
                                   const float* __restrict__ b,
                                   float* __restrict__ ss) {
  int c = threadIdx.x;
  if (c < 128) {
    float mean = stats[c] * (1.f / NN);
    float var  = stats[128 + c] * (1.f / NN) - mean * mean;
    var = fmaxf(var, 0.f);
    float sc = g[c] * rsqrtf(var + EPSV);
    float sh = b[c] - mean * sc;
    ss[c] = sc; ss[128 + c] = sh;
    stats[c] = 0.f; stats[128 + c] = 0.f;
  }
}

__global__ __launch_bounds__(256) void bn_apply_kernel(const float4* __restrict__ y4,
                                                       const float4* __restrict__ ss4,
                                                       ushort4* __restrict__ xb) {
  int i = blockIdx.x * blockDim.x + threadIdx.x;
  const int total = NN * (DD / 4);
  if (i >= total) return;
  int c4 = i & 31;
  float4 v = y4[i], sc = ss4[c4], sh = ss4[32 + c4];
  ushort4 o;
  o.x = f2bf(fmaf(v.x, sc.x, sh.x));
  o.y = f2bf(fmaf(v.y, sc.y, sh.y));
  o.z = f2bf(fmaf(v.z, sc.z, sh.z));
  o.w = f2bf(fmaf(v.w, sc.w, sh.w));
  xb[i] = o;
}

// ---------- final projection [N,128](bf16) @ [128,5] + bias ----------
__global__ __launch_bounds__(256) void proj_kernel(const unsigned short* __restrict__ x,
                                                   const float* __restrict__ Wp,
                                                   const float* __restrict__ bp,
                                                   void* __restrict__ out,
                                                   const int* __restrict__ flag) {
  __shared__ float W[DD * CC];
  __shared__ float bias[CC];
  for (int i = threadIdx.x; i < DD * CC; i += 256) W[i] = Wp[i];
  if (threadIdx.x < CC) bias[threadIdx.x] = bp[threadIdx.x];
  __syncthreads();
  int n = blockIdx.x * blockDim.x + threadIdx.x;
  if (n >= NN) return;
  float acc[CC];
#pragma unroll
  for (int c = 0; c < CC; c++) acc[c] = bias[c];
  const ushort4* xp = (const ushort4*)(x + (size_t)n * DD);
#pragma unroll
  for (int k4 = 0; k4 < DD / 4; k4++) {
    ushort4 u = xp[k4];
    float a0 = bfu2f(u.x), a1 = bfu2f(u.y), a2 = bfu2f(u.z), a3 = bfu2f(u.w);
    const float* w = &W[k4 * 4 * CC];
#pragma unroll
    for (int c = 0; c < CC; c++)
      acc[c] += a0 * w[c] + a1 * w[CC + c] + a2 * w[2 * CC + c] + a3 * w[3 * CC + c];
  }
  if (*flag) {
    __hip_bfloat16* o16 = (__hip_bfloat16*)out;
#pragma unroll
    for (int c = 0; c < CC; c++) o16[(size_t)n * CC + c] = __float2bfloat16(acc[c]);
  } else {
    float* o32 = (float*)out;
#pragma unroll
    for (int c = 0; c < CC; c++) o32[(size_t)n * CC + c] = acc[c];
  }
}

extern "C" void kernel_launch(void* const* d_in, const int* in_sizes, int n_in,
                              void* d_out, int out_size, void* d_ws, size_t ws_size,
                              hipStream_t stream) {
  const int* ei = (const int*)d_in[1];

  char* p = (char*)d_ws;
  auto carve = [&](size_t bytes) { char* r = p; p += (bytes + 255) & ~(size_t)255; return (void*)r; };
  unsigned short* xb   = (unsigned short*)carve((size_t)NN * DD * 2);
  unsigned short* qkv  = (unsigned short*)carve((size_t)NN * 384 * 2);
  unsigned short* t1   = (unsigned short*)carve((size_t)NN * DD * 2);
  unsigned short* hbuf = (unsigned short*)carve((size_t)NN * FFD * 2);
  float* y             = (float*)carve((size_t)NN * DD * 4);
  float* stats = (float*)carve(256 * 4);
  float* ss    = (float*)carve(256 * 4);
  int* row_ptr = (int*)carve((size_t)(NN + 1) * 4);
  int* cursor  = (int*)carve((size_t)NN * 4);
  int* csr_src = (int*)carve((size_t)EE * 4);
  int* flag    = (int*)carve(256);
  int* partials = (int*)carve(256 * 4);
  unsigned short* qkvT = (unsigned short*)carve((size_t)LL * 384 * DD * 2);
  unsigned short* WoT  = (unsigned short*)carve((size_t)LL * DD * DD * 2);
  unsigned short* W1T  = (unsigned short*)carve((size_t)LL * FFD * DD * 2);
  unsigned short* W2T  = (unsigned short*)carve((size_t)LL * DD * FFD * 2);
  float* g1_f  = (float*)carve((size_t)LL * DD * 4);
  float* bn1_f = (float*)carve((size_t)LL * DD * 4);
  float* bf1_f = (float*)carve((size_t)LL * FFD * 4);
  float* bf2_f = (float*)carve((size_t)LL * DD * 4);
  float* g2_f  = (float*)carve((size_t)LL * DD * 4);
  float* bn2_f = (float*)carve((size_t)LL * DD * 4);
  float* Wp_f  = (float*)carve((size_t)DD * CC * 4);
  float* bp_f  = (float*)carve((size_t)CC * 4);
  size_t need = (size_t)(p - (char*)d_ws);
  if (need > ws_size) {
    fprintf(stderr, "kernel_launch: workspace too small: need %zu, have %zu\n", need, ws_size);
    return;
  }

  const int* src  = ei;
  const int* dstp = ei + EE;

  detect_kernel<<<1, 64, 0, stream>>>((const unsigned int*)d_in[6], flag);
  to_bf16_kernel<<<(NN * DD + 255) / 256, 256, 0, stream>>>(d_in[0], xb, NN * DD, flag);

  // batched small-param converts (one dispatch)
  {
    ConvJobs j;
    j.in[0] = d_in[6];  j.out[0] = g1_f;  j.n[0] = LL * DD;
    j.in[1] = d_in[7];  j.out[1] = bn1_f; j.n[1] = LL * DD;
    j.in[2] = d_in[9];  j.out[2] = bf1_f; j.n[2] = LL * FFD;
    j.in[3] = d_in[11]; j.out[3] = bf2_f; j.n[3] = LL * DD;
    j.in[4] = d_in[12]; j.out[4] = g2_f;  j.n[4] = LL * DD;
    j.in[5] = d_in[13]; j.out[5] = bn2_f; j.n[5] = LL * DD;
    j.in[6] = d_in[14]; j.out[6] = Wp_f;  j.n[6] = DD * CC;
    j.in[7] = d_in[15]; j.out[7] = bp_f;  j.n[7] = CC;
    convert_batch_kernel<<<8, 256, 0, stream>>>(j, flag);
  }

  // batched weight transposes (4 dispatches)
  t_qkv_kernel<<<dim3(DD, 3, LL), 256, 0, stream>>>(d_in[2], d_in[3], d_in[4], qkvT, flag);
  t_w_kernel<<<dim3(DD, LL), 256, 0, stream>>>(d_in[5], WoT, DD, DD, flag);
  t_w_kernel<<<dim3(DD, LL), 256, 0, stream>>>(d_in[8], W1T, DD, FFD, flag);
  t_w_kernel<<<dim3(FFD, LL), 256, 0, stream>>>(d_in[10], W2T, FFD, DD, flag);

  // stats zero (bn_finalize re-zeroes after each use)
  zero_kernel<<<1, 256, 0, stream>>>((int*)stats, 256);

  // CSR build with parallel scan
  const int NB = (NN + 255) / 256;  // 196
  zero_kernel<<<(NN + 255) / 256, 256, 0, stream>>>(cursor, NN);
  count_kernel<<<(EE + 255) / 256, 256, 0, stream>>>(dstp, cursor);
  scan1_kernel<<<NB, 256, 0, stream>>>(cursor, row_ptr, partials);
  scan2_kernel<<<1, 256, 0, stream>>>(partials, NB);
  scan3_kernel<<<NB, 256, 0, stream>>>(row_ptr, partials);
  zero_kernel<<<(NN + 255) / 256, 256, 0, stream>>>(cursor, NN);
  fill_kernel<<<(EE + 255) / 256, 256, 0, stream>>>(src, dstp, row_ptr, cursor, csr_src);

  const int gm = (NN + 127) / 128;
  for (int layer = 0; layer < LL; layer++) {
    const unsigned short* qkvT_l = qkvT + (size_t)layer * 384 * DD;
    const unsigned short* WoT_l  = WoT  + (size_t)layer * DD * DD;
    const unsigned short* W1T_l  = W1T  + (size_t)layer * FFD * DD;
    const unsigned short* W2T_l  = W2T  + (size_t)layer * DD * FFD;

    mfma_gemm<128, false, false, false, true, false><<<dim3(gm, 3), 256, 0, stream>>>(
        xb, qkvT_l, nullptr, nullptr, qkv, nullptr, NN, 384);
    attn_kernel<<<(NN * HH + 255) / 256, 256, 0, stream>>>(qkv, row_ptr, csr_src, t1);
    // out-proj + residual -> y (fp32) with fused BN stats
    mfma_gemm<128, false, false, true, false, true><<<dim3(gm, 1), 256, 0, stream>>>(
        t1, WoT_l, nullptr, xb, y, stats, NN, 128);
    bn_finalize_kernel<<<1, 128, 0, stream>>>(stats, g1_f + (size_t)layer * DD, bn1_f + (size_t)layer * DD, ss);
    bn_apply_kernel<<<(NN * 32 + 255) / 256, 256, 0, stream>>>((const float4*)y, (const float4*)ss, (ushort4*)xb);

    mfma_gemm<128, true, true, false, true, false><<<dim3(gm, 2), 256, 0, stream>>>(
        xb, W1T_l, bf1_f + (size_t)layer * FFD, nullptr, hbuf, nullptr, NN, 256);
    mfma_gemm<256, false, true, true, false, true><<<dim3(gm, 1), 256, 0, stream>>>(
        hbuf, W2T_l, bf2_f + (size_t)layer * DD, xb, y, stats, NN, 128);
    bn_finalize_kernel<<<1, 128, 0, stream>>>(stats, g2_f + (size_t)layer * DD, bn2_f + (size_t)layer * DD, ss);
    bn_apply_kernel<<<(NN * 32 + 255) / 256, 256, 0, stream>>>((const float4*)y, (const float4*)ss, (ushort4*)xb);
  }

  proj_kernel<<<(NN + 255) / 256, 256, 0, stream>>>(xb, Wp_f, bp_f, d_out, flag);
}